// Round 4
// baseline (406.083 us; speedup 1.0000x reference)
//
#include <hip/hip_runtime.h>
#include <hip/hip_cooperative_groups.h>
#include <stdint.h>

namespace cg = cooperative_groups;

#define NBINS 1000
#define GRID  1024          // cooperative grid: 4 blocks/CU on 256 CUs
#define NCOPY 16            // interleaved global histogram copies

// W layout (uints):
//   [0 .. 2*GRID)                     per-block {min,max} as raw float bits
//   [HBASE .. HBASE + NCOPY*2*NBINS)  hist copies: copy c = hp[1000] then ht[1000]
#define HBASE (2 * GRID)

__device__ __forceinline__ void mm4(float4 v, float& mn, float& mx) {
    mn = fminf(mn, fminf(fminf(v.x, v.y), fminf(v.z, v.w)));
    mx = fmaxf(mx, fmaxf(fmaxf(v.x, v.y), fmaxf(v.z, v.w)));
}

// count of v <= x_j  ==  sum_{k<=j} hist[k]  with  hist bin k = ceil((v-lo)/dx)
__device__ __forceinline__ int binof(float v, float lo, float inv_dx) {
    float u = (v - lo) * inv_dx;
    int k = (int)ceilf(u);
    return min(max(k, 0), NBINS - 1);
}

__device__ __forceinline__ unsigned agent_ld(const unsigned* a) {
    return __hip_atomic_load(a, __ATOMIC_RELAXED, __HIP_MEMORY_SCOPE_AGENT);
}

__global__ void __launch_bounds__(256, 4) crps_fused(
        const float* __restrict__ p, const float* __restrict__ t,
        long long n, unsigned* __restrict__ W, float* __restrict__ out) {
    cg::grid_group grid = cg::this_grid();
    const int tid = threadIdx.x;
    const int bid = blockIdx.x;

    __shared__ float sred[256];
    __shared__ unsigned hp[2][NBINS];
    __shared__ unsigned ht[2][NBINS];
    __shared__ unsigned long long su[256];
    __shared__ double rd[256];

    // zero the global hist copies while phase A streams (phase C writes after sync)
    if (bid < 64) {
        const int per = (NCOPY * 2 * NBINS) / 64;  // 500
        int base = HBASE + bid * per;
        for (int z = tid; z < per; z += 256) W[base + z] = 0u;
    }

    const long long n4 = n >> 2;
    const float4* p4 = (const float4*)p;
    const float4* t4 = (const float4*)t;
    const long long idx = (long long)bid * 256 + tid;
    const long long stride = (long long)GRID * 256;

    // ---------------- phase A: global min/max (grid-stride, 4x unroll) ----------------
    float mn = __builtin_inff(), mx = -__builtin_inff();
    long long i = idx;
    for (; i + 3 * stride < n4; i += 4 * stride) {
        float4 a0 = p4[i];
        float4 a1 = p4[i + stride];
        float4 a2 = p4[i + 2 * stride];
        float4 a3 = p4[i + 3 * stride];
        float4 b0 = t4[i];
        float4 b1 = t4[i + stride];
        float4 b2 = t4[i + 2 * stride];
        float4 b3 = t4[i + 3 * stride];
        mm4(a0, mn, mx); mm4(a1, mn, mx); mm4(a2, mn, mx); mm4(a3, mn, mx);
        mm4(b0, mn, mx); mm4(b1, mn, mx); mm4(b2, mn, mx); mm4(b3, mn, mx);
    }
    for (; i < n4; i += stride) { mm4(p4[i], mn, mx); mm4(t4[i], mn, mx); }
    for (long long j = (n4 << 2) + idx; j < n; j += stride) {
        float a = p[j], b = t[j];
        mn = fminf(mn, fminf(a, b));
        mx = fmaxf(mx, fmaxf(a, b));
    }
    sred[tid] = mn;
    __syncthreads();
    for (int s = 128; s > 0; s >>= 1) {
        if (tid < s) sred[tid] = fminf(sred[tid], sred[tid + s]);
        __syncthreads();
    }
    if (tid == 0) W[2 * bid] = __float_as_uint(sred[0]);
    __syncthreads();
    sred[tid] = mx;
    __syncthreads();
    for (int s = 128; s > 0; s >>= 1) {
        if (tid < s) sred[tid] = fmaxf(sred[tid], sred[tid + s]);
        __syncthreads();
    }
    if (tid == 0) W[2 * bid + 1] = __float_as_uint(sred[0]);

    grid.sync();

    // ---------------- phase B: reduce per-block slots -> lo/hi ----------------
    float lmn = __builtin_inff(), lmx = -__builtin_inff();
    for (int s2 = tid; s2 < GRID; s2 += 256) {
        lmn = fminf(lmn, __uint_as_float(agent_ld(&W[2 * s2])));
        lmx = fmaxf(lmx, __uint_as_float(agent_ld(&W[2 * s2 + 1])));
    }
    sred[tid] = lmn;
    __syncthreads();
    for (int s = 128; s > 0; s >>= 1) {
        if (tid < s) sred[tid] = fminf(sred[tid], sred[tid + s]);
        __syncthreads();
    }
    const float lo = sred[0];
    __syncthreads();
    sred[tid] = lmx;
    __syncthreads();
    for (int s = 128; s > 0; s >>= 1) {
        if (tid < s) sred[tid] = fmaxf(sred[tid], sred[tid + s]);
        __syncthreads();
    }
    const float hi = sred[0];
    const float inv_dx = (float)(NBINS - 1) / (hi - lo);

    // zero LDS histograms (2-way split to halve same-bank atomic conflicts)
    for (int z = tid; z < NBINS; z += 256) {
        hp[0][z] = 0u; hp[1][z] = 0u; ht[0][z] = 0u; ht[1][z] = 0u;
    }
    __syncthreads();

    // ---------------- phase C: histogram (grid-stride, 4x unroll) ----------------
    const int sub = (tid >> 6) & 1;  // alternate waves use alternate LDS copies
    unsigned* mhp = hp[sub];
    unsigned* mht = ht[sub];
    i = idx;
    for (; i + 3 * stride < n4; i += 4 * stride) {
        float4 a0 = p4[i];
        float4 a1 = p4[i + stride];
        float4 a2 = p4[i + 2 * stride];
        float4 a3 = p4[i + 3 * stride];
        float4 b0 = t4[i];
        float4 b1 = t4[i + stride];
        float4 b2 = t4[i + 2 * stride];
        float4 b3 = t4[i + 3 * stride];
        atomicAdd(&mhp[binof(a0.x, lo, inv_dx)], 1u);
        atomicAdd(&mhp[binof(a0.y, lo, inv_dx)], 1u);
        atomicAdd(&mhp[binof(a0.z, lo, inv_dx)], 1u);
        atomicAdd(&mhp[binof(a0.w, lo, inv_dx)], 1u);
        atomicAdd(&mhp[binof(a1.x, lo, inv_dx)], 1u);
        atomicAdd(&mhp[binof(a1.y, lo, inv_dx)], 1u);
        atomicAdd(&mhp[binof(a1.z, lo, inv_dx)], 1u);
        atomicAdd(&mhp[binof(a1.w, lo, inv_dx)], 1u);
        atomicAdd(&mhp[binof(a2.x, lo, inv_dx)], 1u);
        atomicAdd(&mhp[binof(a2.y, lo, inv_dx)], 1u);
        atomicAdd(&mhp[binof(a2.z, lo, inv_dx)], 1u);
        atomicAdd(&mhp[binof(a2.w, lo, inv_dx)], 1u);
        atomicAdd(&mhp[binof(a3.x, lo, inv_dx)], 1u);
        atomicAdd(&mhp[binof(a3.y, lo, inv_dx)], 1u);
        atomicAdd(&mhp[binof(a3.z, lo, inv_dx)], 1u);
        atomicAdd(&mhp[binof(a3.w, lo, inv_dx)], 1u);
        atomicAdd(&mht[binof(b0.x, lo, inv_dx)], 1u);
        atomicAdd(&mht[binof(b0.y, lo, inv_dx)], 1u);
        atomicAdd(&mht[binof(b0.z, lo, inv_dx)], 1u);
        atomicAdd(&mht[binof(b0.w, lo, inv_dx)], 1u);
        atomicAdd(&mht[binof(b1.x, lo, inv_dx)], 1u);
        atomicAdd(&mht[binof(b1.y, lo, inv_dx)], 1u);
        atomicAdd(&mht[binof(b1.z, lo, inv_dx)], 1u);
        atomicAdd(&mht[binof(b1.w, lo, inv_dx)], 1u);
        atomicAdd(&mht[binof(b2.x, lo, inv_dx)], 1u);
        atomicAdd(&mht[binof(b2.y, lo, inv_dx)], 1u);
        atomicAdd(&mht[binof(b2.z, lo, inv_dx)], 1u);
        atomicAdd(&mht[binof(b2.w, lo, inv_dx)], 1u);
        atomicAdd(&mht[binof(b3.x, lo, inv_dx)], 1u);
        atomicAdd(&mht[binof(b3.y, lo, inv_dx)], 1u);
        atomicAdd(&mht[binof(b3.z, lo, inv_dx)], 1u);
        atomicAdd(&mht[binof(b3.w, lo, inv_dx)], 1u);
    }
    for (; i < n4; i += stride) {
        float4 a = p4[i];
        float4 b = t4[i];
        atomicAdd(&mhp[binof(a.x, lo, inv_dx)], 1u);
        atomicAdd(&mhp[binof(a.y, lo, inv_dx)], 1u);
        atomicAdd(&mhp[binof(a.z, lo, inv_dx)], 1u);
        atomicAdd(&mhp[binof(a.w, lo, inv_dx)], 1u);
        atomicAdd(&mht[binof(b.x, lo, inv_dx)], 1u);
        atomicAdd(&mht[binof(b.y, lo, inv_dx)], 1u);
        atomicAdd(&mht[binof(b.z, lo, inv_dx)], 1u);
        atomicAdd(&mht[binof(b.w, lo, inv_dx)], 1u);
    }
    for (long long j = (n4 << 2) + idx; j < n; j += stride) {
        atomicAdd(&mhp[binof(p[j], lo, inv_dx)], 1u);
        atomicAdd(&mht[binof(t[j], lo, inv_dx)], 1u);
    }
    __syncthreads();

    // flush into one of NCOPY interleaved copies; stagger start to spread bursts
    unsigned* cpb = W + HBASE + (bid & (NCOPY - 1)) * (2 * NBINS);
    int shift = (int)((bid * 61u) % (unsigned)NBINS);
    for (int k = tid; k < NBINS; k += 256) {
        int b = k + shift;
        if (b >= NBINS) b -= NBINS;
        unsigned c0 = hp[0][b] + hp[1][b];
        unsigned c1 = ht[0][b] + ht[1][b];
        if (c0) atomicAdd(&cpb[b], c0);
        if (c1) atomicAdd(&cpb[NBINS + b], c1);
    }

    grid.sync();

    // ---------------- finalize: block 0 only ----------------
    if (bid != 0) return;

    // sum the NCOPY copies: 4 consecutive bins per thread, packed u64 (cp low, ct high)
    int j0 = tid * 4;
    unsigned long long b0 = 0ull, b1 = 0ull, b2 = 0ull, b3 = 0ull;
    if (j0 < NBINS) {
        unsigned cp0 = 0, cp1 = 0, cp2 = 0, cp3 = 0;
        unsigned ct0 = 0, ct1 = 0, ct2 = 0, ct3 = 0;
        for (int c = 0; c < NCOPY; ++c) {
            const unsigned* base = W + HBASE + c * (2 * NBINS);
            cp0 += agent_ld(&base[j0 + 0]);
            cp1 += agent_ld(&base[j0 + 1]);
            cp2 += agent_ld(&base[j0 + 2]);
            cp3 += agent_ld(&base[j0 + 3]);
            ct0 += agent_ld(&base[NBINS + j0 + 0]);
            ct1 += agent_ld(&base[NBINS + j0 + 1]);
            ct2 += agent_ld(&base[NBINS + j0 + 2]);
            ct3 += agent_ld(&base[NBINS + j0 + 3]);
        }
        b0 = (unsigned long long)cp0 | ((unsigned long long)ct0 << 32);
        b1 = (unsigned long long)cp1 | ((unsigned long long)ct1 << 32);
        b2 = (unsigned long long)cp2 | ((unsigned long long)ct2 << 32);
        b3 = (unsigned long long)cp3 | ((unsigned long long)ct3 << 32);
    }
    // thread-local inclusive prefix (counts < 2^25: halves never carry-cross)
    unsigned long long l0 = b0, l1 = l0 + b1, l2 = l1 + b2, l3 = l2 + b3;
    unsigned long long T = l3;
    su[tid] = T;
    __syncthreads();
    for (int off = 1; off < 256; off <<= 1) {
        unsigned long long v = (tid >= off) ? su[tid - off] : 0ull;
        __syncthreads();
        su[tid] += v;
        __syncthreads();
    }
    unsigned long long E = su[tid] - T;  // exclusive prefix of this thread's 4 bins

    double ys = 0.0;
    if (j0 < NBINS) {
        float invn = 1.0f / (float)n;
        unsigned long long incl[4] = { E + l0, E + l1, E + l2, E + l3 };
        for (int q = 0; q < 4; ++q) {
            int j = j0 + q;
            unsigned cpv = (unsigned)(incl[q] & 0xFFFFFFFFull);
            unsigned ctv = (unsigned)(incl[q] >> 32);
            float d = (float)cpv * invn - (float)ctv * invn;
            float yy = d * d;
            float w = (j == 0 || j == NBINS - 1) ? 0.5f : 1.0f;
            ys += (double)yy * (double)w;
        }
    }
    rd[tid] = ys;
    __syncthreads();
    for (int s = 128; s > 0; s >>= 1) {
        if (tid < s) rd[tid] += rd[tid + s];
        __syncthreads();
    }
    if (tid == 0) {
        double dx = (double)(hi - lo) / (double)(NBINS - 1);
        out[0] = (float)(rd[0] * dx);
    }
}

extern "C" void kernel_launch(void* const* d_in, const int* in_sizes, int n_in,
                              void* d_out, int out_size, void* d_ws, size_t ws_size,
                              hipStream_t stream) {
    const float* p = (const float*)d_in[0];
    const float* t = (const float*)d_in[1];
    float* out = (float*)d_out;
    long long n = (long long)in_sizes[0];
    unsigned* W = (unsigned*)d_ws;

    void* args[] = { (void*)&p, (void*)&t, (void*)&n, (void*)&W, (void*)&out };
    hipLaunchCooperativeKernel((const void*)crps_fused, dim3(GRID), dim3(256),
                               args, 0, stream);
}

// Round 5
// 210.530 us; speedup vs baseline: 1.9289x; 1.9289x over previous
//
#include <hip/hip_runtime.h>
#include <stdint.h>

#define NBINS 1000
#define MMB   2048          // minmax grid blocks == number of min/max slots
#define HB    1024          // hist grid blocks
#define NCOPY 16            // interleaved global histogram copies (power of 2)

// W layout (uints):
//   [0 .. 2*MMB)                      per-block {min,max} as raw float bits
//   [HBASE .. HBASE + NCOPY*2*NBINS)  hist copies: copy c = hp[1000] then ht[1000]
//   [CNT]                             done-counter for last-block finalize
#define HBASE (2 * MMB)
#define CNT   (HBASE + NCOPY * 2 * NBINS)

__device__ __forceinline__ void mm4(float4 v, float& mn, float& mx) {
    mn = fminf(mn, fminf(fminf(v.x, v.y), fminf(v.z, v.w)));
    mx = fmaxf(mx, fmaxf(fmaxf(v.x, v.y), fmaxf(v.z, v.w)));
}

__global__ void __launch_bounds__(256) minmax_kernel(
        const float* __restrict__ p, const float* __restrict__ t,
        long long n, unsigned* __restrict__ W) {
    // first 64 blocks zero the global hist copies + counter (hist launches after us)
    if (blockIdx.x < 64) {
        const int per = (NCOPY * 2 * NBINS) / 64;  // 500
        int base = HBASE + blockIdx.x * per;
        for (int i = threadIdx.x; i < per; i += 256) W[base + i] = 0u;
        if (blockIdx.x == 0 && threadIdx.x == 0) W[CNT] = 0u;
    }

    long long n4 = n >> 2;
    const float4* p4 = (const float4*)p;
    const float4* t4 = (const float4*)t;
    float mn = __builtin_inff();
    float mx = -__builtin_inff();
    long long idx = (long long)blockIdx.x * blockDim.x + threadIdx.x;
    long long stride = (long long)gridDim.x * blockDim.x;

    long long i = idx;
    // 4x unrolled grid-stride: 8 independent float4 loads in flight
    for (; i + 3 * stride < n4; i += 4 * stride) {
        float4 a0 = p4[i];
        float4 a1 = p4[i + stride];
        float4 a2 = p4[i + 2 * stride];
        float4 a3 = p4[i + 3 * stride];
        float4 b0 = t4[i];
        float4 b1 = t4[i + stride];
        float4 b2 = t4[i + 2 * stride];
        float4 b3 = t4[i + 3 * stride];
        mm4(a0, mn, mx); mm4(a1, mn, mx); mm4(a2, mn, mx); mm4(a3, mn, mx);
        mm4(b0, mn, mx); mm4(b1, mn, mx); mm4(b2, mn, mx); mm4(b3, mn, mx);
    }
    for (; i < n4; i += stride) {
        mm4(p4[i], mn, mx);
        mm4(t4[i], mn, mx);
    }
    for (long long j = (n4 << 2) + idx; j < n; j += stride) {
        float a = p[j], b = t[j];
        mn = fminf(mn, fminf(a, b));
        mx = fmaxf(mx, fmaxf(a, b));
    }

    __shared__ float smin[256];
    __shared__ float smax[256];
    int tid = threadIdx.x;
    smin[tid] = mn; smax[tid] = mx;
    __syncthreads();
    for (int s = 128; s > 0; s >>= 1) {
        if (tid < s) {
            smin[tid] = fminf(smin[tid], smin[tid + s]);
            smax[tid] = fmaxf(smax[tid], smax[tid + s]);
        }
        __syncthreads();
    }
    if (tid == 0) {
        W[2 * blockIdx.x]     = __float_as_uint(smin[0]);
        W[2 * blockIdx.x + 1] = __float_as_uint(smax[0]);
    }
}

// count of v <= x_j  ==  sum_{k<=j} hist[k]  with  hist bin k = ceil((v-lo)/dx)
__device__ __forceinline__ int binof(float v, float lo, float inv_dx) {
    float u = (v - lo) * inv_dx;
    int k = (int)ceilf(u);
    return min(max(k, 0), NBINS - 1);
}

__device__ __forceinline__ void hist4v(float4 v, unsigned* h, float lo, float inv_dx) {
    atomicAdd(&h[binof(v.x, lo, inv_dx)], 1u);
    atomicAdd(&h[binof(v.y, lo, inv_dx)], 1u);
    atomicAdd(&h[binof(v.z, lo, inv_dx)], 1u);
    atomicAdd(&h[binof(v.w, lo, inv_dx)], 1u);
}

__device__ __forceinline__ unsigned agent_ld(const unsigned* a) {
    return __hip_atomic_load(a, __ATOMIC_RELAXED, __HIP_MEMORY_SCOPE_AGENT);
}

__global__ void __launch_bounds__(256) hist_kernel(
        const float* __restrict__ p, const float* __restrict__ t,
        long long n, unsigned* __restrict__ W, float* __restrict__ out) {
    __shared__ unsigned hp[NBINS];
    __shared__ unsigned ht[NBINS];
    __shared__ float sred[256];
    __shared__ unsigned done;
    __shared__ unsigned long long su[256];
    __shared__ double rd[256];
    int tid = threadIdx.x;

    // lo/hi from the MMB per-block slots (written by previous kernel)
    float lmn = __builtin_inff(), lmx = -__builtin_inff();
    for (int i = tid; i < MMB; i += 256) {
        lmn = fminf(lmn, __uint_as_float(W[2 * i]));
        lmx = fmaxf(lmx, __uint_as_float(W[2 * i + 1]));
    }
    for (int i = tid; i < NBINS; i += 256) { hp[i] = 0u; ht[i] = 0u; }
    sred[tid] = lmn;
    __syncthreads();
    for (int s = 128; s > 0; s >>= 1) {
        if (tid < s) sred[tid] = fminf(sred[tid], sred[tid + s]);
        __syncthreads();
    }
    float lo = sred[0];
    __syncthreads();
    sred[tid] = lmx;
    __syncthreads();
    for (int s = 128; s > 0; s >>= 1) {
        if (tid < s) sred[tid] = fmaxf(sred[tid], sred[tid + s]);
        __syncthreads();
    }
    float hi = sred[0];
    __syncthreads();

    float inv_dx = (float)(NBINS - 1) / (hi - lo);

    long long n4 = n >> 2;
    const float4* p4 = (const float4*)p;
    const float4* t4 = (const float4*)t;
    long long idx = (long long)blockIdx.x * blockDim.x + tid;
    long long stride = (long long)gridDim.x * blockDim.x;

    long long i = idx;
    // 4x unrolled grid-stride: 8 independent float4 loads in flight
    for (; i + 3 * stride < n4; i += 4 * stride) {
        float4 a0 = p4[i];
        float4 a1 = p4[i + stride];
        float4 a2 = p4[i + 2 * stride];
        float4 a3 = p4[i + 3 * stride];
        float4 b0 = t4[i];
        float4 b1 = t4[i + stride];
        float4 b2 = t4[i + 2 * stride];
        float4 b3 = t4[i + 3 * stride];
        hist4v(a0, hp, lo, inv_dx); hist4v(a1, hp, lo, inv_dx);
        hist4v(a2, hp, lo, inv_dx); hist4v(a3, hp, lo, inv_dx);
        hist4v(b0, ht, lo, inv_dx); hist4v(b1, ht, lo, inv_dx);
        hist4v(b2, ht, lo, inv_dx); hist4v(b3, ht, lo, inv_dx);
    }
    for (; i < n4; i += stride) {
        hist4v(p4[i], hp, lo, inv_dx);
        hist4v(t4[i], ht, lo, inv_dx);
    }
    for (long long j = (n4 << 2) + idx; j < n; j += stride) {
        atomicAdd(&hp[binof(p[j], lo, inv_dx)], 1u);
        atomicAdd(&ht[binof(t[j], lo, inv_dx)], 1u);
    }
    __syncthreads();

    // flush into one of NCOPY interleaved copies; stagger start to spread bursts
    unsigned* cpb = W + HBASE + (blockIdx.x & (NCOPY - 1)) * (2 * NBINS);
    int shift = (int)((blockIdx.x * 61u) % (unsigned)NBINS);
    for (int k = tid; k < NBINS; k += 256) {
        int b = k + shift;
        if (b >= NBINS) b -= NBINS;
        unsigned c0 = hp[b];
        unsigned c1 = ht[b];
        if (c0) atomicAdd(&cpb[b], c0);
        if (c1) atomicAdd(&cpb[NBINS + b], c1);
    }

    // ---- last-arriving block finalizes (no spin: deadlock-free) ----
    __syncthreads();   // all flush atomics of this block issued
    if (tid == 0) {
        __threadfence();
        done = atomicAdd(&W[CNT], 1u);
    }
    __syncthreads();
    if (done != (unsigned)(gridDim.x - 1)) return;
    __threadfence();

    // sum the NCOPY copies: 4 consecutive bins per thread, packed u64 (cp low, ct high)
    int j0 = tid * 4;
    unsigned long long b0 = 0ull, b1 = 0ull, b2 = 0ull, b3 = 0ull;
    if (j0 < NBINS) {
        unsigned cp0 = 0, cp1 = 0, cp2 = 0, cp3 = 0;
        unsigned ct0 = 0, ct1 = 0, ct2 = 0, ct3 = 0;
        for (int c = 0; c < NCOPY; ++c) {
            const unsigned* base = W + HBASE + c * (2 * NBINS);
            cp0 += agent_ld(&base[j0 + 0]);
            cp1 += agent_ld(&base[j0 + 1]);
            cp2 += agent_ld(&base[j0 + 2]);
            cp3 += agent_ld(&base[j0 + 3]);
            ct0 += agent_ld(&base[NBINS + j0 + 0]);
            ct1 += agent_ld(&base[NBINS + j0 + 1]);
            ct2 += agent_ld(&base[NBINS + j0 + 2]);
            ct3 += agent_ld(&base[NBINS + j0 + 3]);
        }
        b0 = (unsigned long long)cp0 | ((unsigned long long)ct0 << 32);
        b1 = (unsigned long long)cp1 | ((unsigned long long)ct1 << 32);
        b2 = (unsigned long long)cp2 | ((unsigned long long)ct2 << 32);
        b3 = (unsigned long long)cp3 | ((unsigned long long)ct3 << 32);
    }
    // thread-local inclusive prefix (counts < 2^25: halves never carry-cross)
    unsigned long long l0 = b0, l1 = l0 + b1, l2 = l1 + b2, l3 = l2 + b3;
    unsigned long long T = l3;
    su[tid] = T;
    __syncthreads();
    for (int off = 1; off < 256; off <<= 1) {
        unsigned long long v = (tid >= off) ? su[tid - off] : 0ull;
        __syncthreads();
        su[tid] += v;
        __syncthreads();
    }
    unsigned long long E = su[tid] - T;  // exclusive prefix of this thread's 4 bins

    double ys = 0.0;
    if (j0 < NBINS) {
        float invn = 1.0f / (float)n;
        unsigned long long incl[4] = { E + l0, E + l1, E + l2, E + l3 };
        for (int q = 0; q < 4; ++q) {
            int j = j0 + q;
            unsigned cpv = (unsigned)(incl[q] & 0xFFFFFFFFull);
            unsigned ctv = (unsigned)(incl[q] >> 32);
            float d = (float)cpv * invn - (float)ctv * invn;
            float yy = d * d;
            float w = (j == 0 || j == NBINS - 1) ? 0.5f : 1.0f;
            ys += (double)yy * (double)w;
        }
    }
    rd[tid] = ys;
    __syncthreads();
    for (int s = 128; s > 0; s >>= 1) {
        if (tid < s) rd[tid] += rd[tid + s];
        __syncthreads();
    }
    if (tid == 0) {
        double dx = (double)(hi - lo) / (double)(NBINS - 1);
        out[0] = (float)(rd[0] * dx);
    }
}

extern "C" void kernel_launch(void* const* d_in, const int* in_sizes, int n_in,
                              void* d_out, int out_size, void* d_ws, size_t ws_size,
                              hipStream_t stream) {
    const float* p = (const float*)d_in[0];
    const float* t = (const float*)d_in[1];
    float* out = (float*)d_out;
    long long n = (long long)in_sizes[0];
    unsigned* W = (unsigned*)d_ws;

    minmax_kernel<<<MMB, 256, 0, stream>>>(p, t, n, W);
    hist_kernel<<<HB, 256, 0, stream>>>(p, t, n, W, out);
}

// Round 7
// 180.550 us; speedup vs baseline: 2.2491x; 1.1660x over previous
//
#include <hip/hip_runtime.h>
#include <stdint.h>

#define NBINS 1000
#define MMB   2048          // minmax grid blocks == number of min/max slots
#define HB    1024          // hist grid blocks
#define NCOPY 16            // interleaved global histogram copies (power of 2)

// W layout (uints):
//   [0 .. 2*MMB)                      per-block {min,max} as raw float bits
//   [HBASE .. HBASE + NCOPY*2*NBINS)  hist copies: copy c = hp[1000] then ht[1000]
#define HBASE (2 * MMB)

__device__ __forceinline__ void mm4(float4 v, float& mn, float& mx) {
    mn = fminf(mn, fminf(fminf(v.x, v.y), fminf(v.z, v.w)));
    mx = fmaxf(mx, fmaxf(fmaxf(v.x, v.y), fmaxf(v.z, v.w)));
}

__global__ void __launch_bounds__(256) minmax_kernel(
        const float* __restrict__ p, const float* __restrict__ t,
        long long n, unsigned* __restrict__ W) {
    // first 64 blocks zero the global hist copies (hist launches after us)
    if (blockIdx.x < 64) {
        const int per = (NCOPY * 2 * NBINS) / 64;  // 500
        int base = HBASE + blockIdx.x * per;
        for (int i = threadIdx.x; i < per; i += 256) W[base + i] = 0u;
    }

    long long n4 = n >> 2;
    const float4* p4 = (const float4*)p;
    const float4* t4 = (const float4*)t;
    float mn = __builtin_inff();
    float mx = -__builtin_inff();
    long long idx = (long long)blockIdx.x * blockDim.x + threadIdx.x;
    long long stride = (long long)gridDim.x * blockDim.x;

    long long i = idx;
    // 4x unrolled grid-stride: 8 independent float4 loads in flight
    for (; i + 3 * stride < n4; i += 4 * stride) {
        float4 a0 = p4[i];
        float4 a1 = p4[i + stride];
        float4 a2 = p4[i + 2 * stride];
        float4 a3 = p4[i + 3 * stride];
        float4 b0 = t4[i];
        float4 b1 = t4[i + stride];
        float4 b2 = t4[i + 2 * stride];
        float4 b3 = t4[i + 3 * stride];
        mm4(a0, mn, mx); mm4(a1, mn, mx); mm4(a2, mn, mx); mm4(a3, mn, mx);
        mm4(b0, mn, mx); mm4(b1, mn, mx); mm4(b2, mn, mx); mm4(b3, mn, mx);
    }
    for (; i < n4; i += stride) {
        mm4(p4[i], mn, mx);
        mm4(t4[i], mn, mx);
    }
    for (long long j = (n4 << 2) + idx; j < n; j += stride) {
        float a = p[j], b = t[j];
        mn = fminf(mn, fminf(a, b));
        mx = fmaxf(mx, fmaxf(a, b));
    }

    __shared__ float smin[256];
    __shared__ float smax[256];
    int tid = threadIdx.x;
    smin[tid] = mn; smax[tid] = mx;
    __syncthreads();
    for (int s = 128; s > 0; s >>= 1) {
        if (tid < s) {
            smin[tid] = fminf(smin[tid], smin[tid + s]);
            smax[tid] = fmaxf(smax[tid], smax[tid + s]);
        }
        __syncthreads();
    }
    if (tid == 0) {
        W[2 * blockIdx.x]     = __float_as_uint(smin[0]);
        W[2 * blockIdx.x + 1] = __float_as_uint(smax[0]);
    }
}

// count of v <= x_j  ==  sum_{k<=j} hist[k]  with  hist bin k = ceil((v-lo)/dx)
__device__ __forceinline__ int binof(float v, float lo, float inv_dx) {
    float u = (v - lo) * inv_dx;
    int k = (int)ceilf(u);
    return min(max(k, 0), NBINS - 1);
}

__device__ __forceinline__ void hist4v(float4 v, unsigned* h, float lo, float inv_dx) {
    atomicAdd(&h[binof(v.x, lo, inv_dx)], 1u);
    atomicAdd(&h[binof(v.y, lo, inv_dx)], 1u);
    atomicAdd(&h[binof(v.z, lo, inv_dx)], 1u);
    atomicAdd(&h[binof(v.w, lo, inv_dx)], 1u);
}

__global__ void __launch_bounds__(256) hist_kernel(
        const float* __restrict__ p, const float* __restrict__ t,
        long long n, unsigned* __restrict__ W) {
    __shared__ unsigned hp[NBINS];
    __shared__ unsigned ht[NBINS];
    __shared__ float sred[256];
    int tid = threadIdx.x;

    // lo/hi from the MMB per-block slots (written by previous kernel)
    float lmn = __builtin_inff(), lmx = -__builtin_inff();
    for (int i = tid; i < MMB; i += 256) {
        lmn = fminf(lmn, __uint_as_float(W[2 * i]));
        lmx = fmaxf(lmx, __uint_as_float(W[2 * i + 1]));
    }
    for (int i = tid; i < NBINS; i += 256) { hp[i] = 0u; ht[i] = 0u; }
    sred[tid] = lmn;
    __syncthreads();
    for (int s = 128; s > 0; s >>= 1) {
        if (tid < s) sred[tid] = fminf(sred[tid], sred[tid + s]);
        __syncthreads();
    }
    float lo = sred[0];
    __syncthreads();
    sred[tid] = lmx;
    __syncthreads();
    for (int s = 128; s > 0; s >>= 1) {
        if (tid < s) sred[tid] = fmaxf(sred[tid], sred[tid + s]);
        __syncthreads();
    }
    float hi = sred[0];
    __syncthreads();

    float inv_dx = (float)(NBINS - 1) / (hi - lo);

    long long n4 = n >> 2;
    const float4* p4 = (const float4*)p;
    const float4* t4 = (const float4*)t;
    long long idx = (long long)blockIdx.x * blockDim.x + tid;
    long long stride = (long long)gridDim.x * blockDim.x;

    long long i = idx;
    // 4x unrolled grid-stride: 8 independent float4 loads in flight
    for (; i + 3 * stride < n4; i += 4 * stride) {
        float4 a0 = p4[i];
        float4 a1 = p4[i + stride];
        float4 a2 = p4[i + 2 * stride];
        float4 a3 = p4[i + 3 * stride];
        float4 b0 = t4[i];
        float4 b1 = t4[i + stride];
        float4 b2 = t4[i + 2 * stride];
        float4 b3 = t4[i + 3 * stride];
        hist4v(a0, hp, lo, inv_dx); hist4v(a1, hp, lo, inv_dx);
        hist4v(a2, hp, lo, inv_dx); hist4v(a3, hp, lo, inv_dx);
        hist4v(b0, ht, lo, inv_dx); hist4v(b1, ht, lo, inv_dx);
        hist4v(b2, ht, lo, inv_dx); hist4v(b3, ht, lo, inv_dx);
    }
    for (; i < n4; i += stride) {
        hist4v(p4[i], hp, lo, inv_dx);
        hist4v(t4[i], ht, lo, inv_dx);
    }
    for (long long j = (n4 << 2) + idx; j < n; j += stride) {
        atomicAdd(&hp[binof(p[j], lo, inv_dx)], 1u);
        atomicAdd(&ht[binof(t[j], lo, inv_dx)], 1u);
    }
    __syncthreads();

    // flush into one of NCOPY interleaved copies; stagger start to spread bursts
    unsigned* cpb = W + HBASE + (blockIdx.x & (NCOPY - 1)) * (2 * NBINS);
    int shift = (int)((blockIdx.x * 61u) % (unsigned)NBINS);
    for (int k = tid; k < NBINS; k += 256) {
        int b = k + shift;
        if (b >= NBINS) b -= NBINS;
        unsigned c0 = hp[b];
        unsigned c1 = ht[b];
        if (c0) atomicAdd(&cpb[b], c0);
        if (c1) atomicAdd(&cpb[NBINS + b], c1);
    }
}

__global__ void __launch_bounds__(256) finalize_kernel(
        const unsigned* __restrict__ W, float* __restrict__ out, long long n) {
    __shared__ unsigned long long su[256];
    __shared__ double rd[256];
    __shared__ float fred[256];
    int tid = threadIdx.x;

    // lo/hi from the MMB slots
    float lmn = __builtin_inff(), lmx = -__builtin_inff();
    for (int i = tid; i < MMB; i += 256) {
        lmn = fminf(lmn, __uint_as_float(W[2 * i]));
        lmx = fmaxf(lmx, __uint_as_float(W[2 * i + 1]));
    }
    fred[tid] = lmn;
    __syncthreads();
    for (int s = 128; s > 0; s >>= 1) {
        if (tid < s) fred[tid] = fminf(fred[tid], fred[tid + s]);
        __syncthreads();
    }
    float lo = fred[0];
    __syncthreads();
    fred[tid] = lmx;
    __syncthreads();
    for (int s = 128; s > 0; s >>= 1) {
        if (tid < s) fred[tid] = fmaxf(fred[tid], fred[tid + s]);
        __syncthreads();
    }
    float hi = fred[0];

    // sum the NCOPY copies: 4 consecutive bins per thread, packed u64 (cp low, ct high)
    int j0 = tid * 4;
    unsigned long long b0 = 0ull, b1 = 0ull, b2 = 0ull, b3 = 0ull;
    if (j0 < NBINS) {
        unsigned cp0 = 0, cp1 = 0, cp2 = 0, cp3 = 0;
        unsigned ct0 = 0, ct1 = 0, ct2 = 0, ct3 = 0;
        for (int c = 0; c < NCOPY; ++c) {
            const unsigned* base = W + HBASE + c * (2 * NBINS);
            cp0 += base[j0 + 0];
            cp1 += base[j0 + 1];
            cp2 += base[j0 + 2];
            cp3 += base[j0 + 3];
            ct0 += base[NBINS + j0 + 0];
            ct1 += base[NBINS + j0 + 1];
            ct2 += base[NBINS + j0 + 2];
            ct3 += base[NBINS + j0 + 3];
        }
        b0 = (unsigned long long)cp0 | ((unsigned long long)ct0 << 32);
        b1 = (unsigned long long)cp1 | ((unsigned long long)ct1 << 32);
        b2 = (unsigned long long)cp2 | ((unsigned long long)ct2 << 32);
        b3 = (unsigned long long)cp3 | ((unsigned long long)ct3 << 32);
    }
    // thread-local inclusive prefix (counts < 2^25: halves never carry-cross)
    unsigned long long l0 = b0, l1 = l0 + b1, l2 = l1 + b2, l3 = l2 + b3;
    unsigned long long T = l3;
    su[tid] = T;
    __syncthreads();
    for (int off = 1; off < 256; off <<= 1) {
        unsigned long long v = (tid >= off) ? su[tid - off] : 0ull;
        __syncthreads();
        su[tid] += v;
        __syncthreads();
    }
    unsigned long long E = su[tid] - T;  // exclusive prefix of this thread's 4 bins

    double ys = 0.0;
    if (j0 < NBINS) {
        float invn = 1.0f / (float)n;
        unsigned long long incl[4] = { E + l0, E + l1, E + l2, E + l3 };
        for (int q = 0; q < 4; ++q) {
            int j = j0 + q;
            unsigned cpv = (unsigned)(incl[q] & 0xFFFFFFFFull);
            unsigned ctv = (unsigned)(incl[q] >> 32);
            float d = (float)cpv * invn - (float)ctv * invn;
            float yy = d * d;
            float w = (j == 0 || j == NBINS - 1) ? 0.5f : 1.0f;
            ys += (double)yy * (double)w;
        }
    }
    rd[tid] = ys;
    __syncthreads();
    for (int s = 128; s > 0; s >>= 1) {
        if (tid < s) rd[tid] += rd[tid + s];
        __syncthreads();
    }
    if (tid == 0) {
        double dx = (double)(hi - lo) / (double)(NBINS - 1);
        out[0] = (float)(rd[0] * dx);
    }
}

extern "C" void kernel_launch(void* const* d_in, const int* in_sizes, int n_in,
                              void* d_out, int out_size, void* d_ws, size_t ws_size,
                              hipStream_t stream) {
    const float* p = (const float*)d_in[0];
    const float* t = (const float*)d_in[1];
    float* out = (float*)d_out;
    long long n = (long long)in_sizes[0];
    unsigned* W = (unsigned*)d_ws;

    minmax_kernel<<<MMB, 256, 0, stream>>>(p, t, n, W);
    hist_kernel<<<HB, 256, 0, stream>>>(p, t, n, W);
    finalize_kernel<<<1, 256, 0, stream>>>(W, out, n);
}